// Round 1
// baseline (489.961 us; speedup 1.0000x reference)
//
#include <hip/hip_runtime.h>

// HopAttentionLayer: B=256, T=64, N=2048, D=128, fp32.
// attention[b,n] = softmax_n( T * dot(context[b,n,:], W[D:2D]) )
//   (tgt_term[b] and T*b0 are constant over n -> cancel in softmax)
// out[b,n,d] = attention[b,n] * context[b,n,d]

#define B_DIM 256
#define T_SCALE 64.0f
#define N_DIM 2048
#define D_DIM 128
#define DVEC  (D_DIM / 4)   // 32 float4 per row
#define BLOCK 1024          // 16 waves

__global__ __launch_bounds__(BLOCK)
void hop_attn_kernel(const float* __restrict__ ctx,
                     const float* __restrict__ W,
                     float* __restrict__ out) {
    const int b    = blockIdx.x;
    const int tid  = threadIdx.x;
    const int wave = tid >> 6;      // 0..15
    const int lane = tid & 63;
    const int sub  = lane & 31;     // lane within 32-lane half
    const int half = lane >> 5;     // 0/1

    __shared__ float s_scores[N_DIM];   // 8 KiB: scores, then exp values
    __shared__ float s_red[16];
    __shared__ float s_bcast[2];

    const float4* ctx4 = (const float4*)(ctx) + (size_t)b * N_DIM * DVEC;
    float4*       out4 = (float4*)(out)       + (size_t)b * N_DIM * DVEC;

    // Wc fragment: lane 'sub' owns Wc[4*sub .. 4*sub+3]
    const float4 wc = ((const float4*)(W + D_DIM))[sub];

    // ---- Phase 1: scores[n] = T * dot(ctx[b,n,:], Wc) ----
    // 16 waves x 2 rows/wave = 32 rows per iteration; 64 iterations.
    for (int it = 0; it < N_DIM / 32; ++it) {
        const int n = it * 32 + wave * 2 + half;
        const float4 v = ctx4[n * DVEC + sub];
        float p = v.x * wc.x + v.y * wc.y + v.z * wc.z + v.w * wc.w;
        // reduce across the 32 'sub' lanes (xor masks < 32 stay in-half)
        #pragma unroll
        for (int m = 1; m < 32; m <<= 1) p += __shfl_xor(p, m, 64);
        if (sub == 0) s_scores[n] = T_SCALE * p;
    }
    __syncthreads();

    // ---- Phase 2a: block max over 2048 scores ----
    float m0 = fmaxf(s_scores[tid], s_scores[tid + BLOCK]);
    #pragma unroll
    for (int m = 1; m < 64; m <<= 1) m0 = fmaxf(m0, __shfl_xor(m0, m, 64));
    if (lane == 0) s_red[wave] = m0;
    __syncthreads();
    if (wave == 0) {
        float v = (lane < 16) ? s_red[lane] : -3.4e38f;
        #pragma unroll
        for (int m = 1; m < 16; m <<= 1) v = fmaxf(v, __shfl_xor(v, m, 64));
        if (lane == 0) s_bcast[0] = v;
    }
    __syncthreads();
    const float gmax = s_bcast[0];

    // ---- Phase 2b: exp + sum ----
    const float e0 = __expf(s_scores[tid] - gmax);
    const float e1 = __expf(s_scores[tid + BLOCK] - gmax);
    s_scores[tid]         = e0;
    s_scores[tid + BLOCK] = e1;
    float sum = e0 + e1;
    #pragma unroll
    for (int m = 1; m < 64; m <<= 1) sum += __shfl_xor(sum, m, 64);
    if (lane == 0) s_red[wave] = sum;
    __syncthreads();
    if (wave == 0) {
        float v = (lane < 16) ? s_red[lane] : 0.0f;
        #pragma unroll
        for (int m = 1; m < 16; m <<= 1) v += __shfl_xor(v, m, 64);
        if (lane == 0) s_bcast[1] = v;
    }
    __syncthreads();
    const float inv = 1.0f / s_bcast[1];

    // ---- Phase 3: out[b,n,:] = (e[n]*inv) * ctx[b,n,:] ----
    // 2048*32 = 65536 float4 per batch; 64 per thread, coalesced.
    #pragma unroll 4
    for (int i = 0; i < (N_DIM * DVEC) / BLOCK; ++i) {
        const int flat = tid + (i << 10);
        const int n    = flat >> 5;                 // row (LDS broadcast read)
        const float w  = s_scores[n] * inv;
        const float4 v = ctx4[flat];
        float4 r;
        r.x = v.x * w; r.y = v.y * w; r.z = v.z * w; r.w = v.w * w;
        out4[flat] = r;
    }
}

extern "C" void kernel_launch(void* const* d_in, const int* in_sizes, int n_in,
                              void* d_out, int out_size, void* d_ws, size_t ws_size,
                              hipStream_t stream) {
    (void)in_sizes; (void)n_in; (void)d_ws; (void)ws_size; (void)out_size;
    // d_in[0] = targetsentence_emb (unused: cancels in softmax)
    // d_in[1] = context_emb, d_in[2] = W, d_in[3] = b (unused: cancels)
    const float* ctx = (const float*)d_in[1];
    const float* W   = (const float*)d_in[2];
    float* out       = (float*)d_out;

    hipLaunchKernelGGL(hop_attn_kernel, dim3(B_DIM), dim3(BLOCK), 0, stream,
                       ctx, W, out);
}

// Round 2
// 478.903 us; speedup vs baseline: 1.0231x; 1.0231x over previous
//
#include <hip/hip_runtime.h>

// HopAttentionLayer: B=256, T=64, N=2048, D=128, fp32.
// attention[b,n] = softmax_n( T * dot(context[b,n,:], W[D:2D]) )
//   (tgt_term[b] and T*b0 are constant over n -> cancel in softmax)
// out[b,n,d] = attention[b,n] * context[b,n,d]
//
// 3-kernel streaming pipeline (R1): the monolithic 256-block version left
// CUs idle (1 wg/CU, barrier drains) and hit only ~4.1 TB/s. Here every
// kernel has an oversubscribed grid and no cross-phase barriers.

#define B_DIM 256
#define N_DIM 2048
#define D_DIM 128
#define DVEC  (D_DIM / 4)   // 32 float4 per row
#define T_SCALE 64.0f

// ---- K1: scores[r] = T * dot(ctx[r,:], Wc), r = b*N + n, flat over B*N ----
// 256 threads = 4 waves = 8 rows/block; one float4 load per thread.
__global__ __launch_bounds__(256)
void k_scores(const float* __restrict__ ctx, const float* __restrict__ W,
              float* __restrict__ scores) {
    const int tid  = threadIdx.x;
    const int wave = tid >> 6;
    const int lane = tid & 63;
    const int sub  = lane & 31;
    const int half = lane >> 5;
    const int r    = blockIdx.x * 8 + wave * 2 + half;

    const float4 wc = ((const float4*)(W + D_DIM))[sub];
    const float4 v  = ((const float4*)ctx)[(size_t)r * DVEC + sub];
    float p = v.x * wc.x + v.y * wc.y + v.z * wc.z + v.w * wc.w;
    #pragma unroll
    for (int m = 1; m < 32; m <<= 1) p += __shfl_xor(p, m, 64);  // in-half
    if (sub == 0) scores[r] = T_SCALE * p;
}

// ---- K2: in-place softmax over each batch's 2048 scores ----
// One block per batch; each thread owns 8 values (2 float4). In-place is
// safe: each thread writes only the elements it read.
__global__ __launch_bounds__(256)
void k_softmax(float* __restrict__ s) {
    const int tid  = threadIdx.x;
    const int wave = tid >> 6;
    const int lane = tid & 63;
    float4* row4 = (float4*)(s + (size_t)blockIdx.x * N_DIM);

    __shared__ float red[4];
    __shared__ float bc[2];

    float4 a = row4[tid];
    float4 c = row4[tid + 256];

    float m0 = fmaxf(fmaxf(fmaxf(a.x, a.y), fmaxf(a.z, a.w)),
                     fmaxf(fmaxf(c.x, c.y), fmaxf(c.z, c.w)));
    #pragma unroll
    for (int m = 1; m < 64; m <<= 1) m0 = fmaxf(m0, __shfl_xor(m0, m, 64));
    if (lane == 0) red[wave] = m0;
    __syncthreads();
    const float gmax = fmaxf(fmaxf(red[0], red[1]), fmaxf(red[2], red[3]));

    a.x = __expf(a.x - gmax); a.y = __expf(a.y - gmax);
    a.z = __expf(a.z - gmax); a.w = __expf(a.w - gmax);
    c.x = __expf(c.x - gmax); c.y = __expf(c.y - gmax);
    c.z = __expf(c.z - gmax); c.w = __expf(c.w - gmax);

    float sum = a.x + a.y + a.z + a.w + c.x + c.y + c.z + c.w;
    #pragma unroll
    for (int m = 1; m < 64; m <<= 1) sum += __shfl_xor(sum, m, 64);
    if (lane == 0) red[wave] = sum;
    __syncthreads();
    const float inv = 1.0f / (red[0] + red[1] + red[2] + red[3]);
    (void)bc;

    a.x *= inv; a.y *= inv; a.z *= inv; a.w *= inv;
    c.x *= inv; c.y *= inv; c.z *= inv; c.w *= inv;
    row4[tid]       = a;
    row4[tid + 256] = c;
}

// ---- K3: out[r,:] = p[r] * ctx[r,:] ----
// 64 consecutive rows per block (2048 float4); p staged in LDS (broadcast
// reads: all 32 lanes of a half-wave hit the same LDS address).
__global__ __launch_bounds__(256)
void k_scale(const float* __restrict__ ctx, const float* __restrict__ p,
             float* __restrict__ out) {
    const int tid = threadIdx.x;
    const size_t base_row = (size_t)blockIdx.x * 64;

    __shared__ float sp[64];
    if (tid < 64) sp[tid] = p[base_row + tid];
    __syncthreads();

    const float4* c4 = (const float4*)ctx + base_row * DVEC;
    float4*       o4 = (float4*)out       + base_row * DVEC;

    #pragma unroll
    for (int i = 0; i < 8; ++i) {
        const int f = i * 256 + tid;
        const float w = sp[f >> 5];
        const float4 v = c4[f];
        float4 r;
        r.x = v.x * w; r.y = v.y * w; r.z = v.z * w; r.w = v.w * w;
        o4[f] = r;
    }
}

extern "C" void kernel_launch(void* const* d_in, const int* in_sizes, int n_in,
                              void* d_out, int out_size, void* d_ws, size_t ws_size,
                              hipStream_t stream) {
    (void)in_sizes; (void)n_in; (void)out_size; (void)ws_size;
    // d_in[0] = targetsentence_emb (unused: cancels in softmax)
    // d_in[1] = context_emb, d_in[2] = W, d_in[3] = b (unused: cancels)
    const float* ctx = (const float*)d_in[1];
    const float* W   = (const float*)d_in[2];
    float* out       = (float*)d_out;
    float* scores    = (float*)d_ws;   // B*N floats = 2 MiB

    hipLaunchKernelGGL(k_scores,  dim3(B_DIM * N_DIM / 8), dim3(256), 0, stream,
                       ctx, W, scores);
    hipLaunchKernelGGL(k_softmax, dim3(B_DIM),             dim3(256), 0, stream,
                       scores);
    hipLaunchKernelGGL(k_scale,   dim3(B_DIM * N_DIM / 64), dim3(256), 0, stream,
                       ctx, scores, out);
}

// Round 3
// 466.271 us; speedup vs baseline: 1.0508x; 1.0271x over previous
//
#include <hip/hip_runtime.h>

// HopAttentionLayer: B=256, T=64, N=2048, D=128, fp32.
// attention[b,n] = softmax_n( T * dot(context[b,n,:], W[D:2D]) )
//   (tgt_term[b] and T*b0 are constant over n -> cancel in softmax)
// out[b,n,d] = attention[b,n] * context[b,n,d]
//
// R2: 3-kernel streaming pipeline + L3-residency tricks:
//  - K3 walks batches in REVERSE of K1's stream order (LIFO: re-read what
//    is still resident in the 256 MiB Infinity Cache first)
//  - K3 uses non-temporal load/store so the 256 MiB output write doesn't
//    evict the ctx lines we want to re-hit.

#define B_DIM 256
#define N_DIM 2048
#define D_DIM 128
#define DVEC  (D_DIM / 4)   // 32 float4 per row
#define T_SCALE 64.0f

typedef float f4v __attribute__((ext_vector_type(4)));

// ---- K1: scores[r] = T * dot(ctx[r,:], Wc), r = b*N + n, flat over B*N ----
// 256 threads = 4 waves = 8 rows/block; one float4 load per thread.
// Normal (caching) loads: this pass populates L2/L3 for K3's re-read.
__global__ __launch_bounds__(256)
void k_scores(const float* __restrict__ ctx, const float* __restrict__ W,
              float* __restrict__ scores) {
    const int tid  = threadIdx.x;
    const int wave = tid >> 6;
    const int lane = tid & 63;
    const int sub  = lane & 31;
    const int half = lane >> 5;
    const int r    = blockIdx.x * 8 + wave * 2 + half;

    const float4 wc = ((const float4*)(W + D_DIM))[sub];
    const float4 v  = ((const float4*)ctx)[(size_t)r * DVEC + sub];
    float p = v.x * wc.x + v.y * wc.y + v.z * wc.z + v.w * wc.w;
    #pragma unroll
    for (int m = 1; m < 32; m <<= 1) p += __shfl_xor(p, m, 64);  // in-half
    if (sub == 0) scores[r] = T_SCALE * p;
}

// ---- K2: in-place softmax over each batch's 2048 scores ----
// One block per batch; each thread owns 8 values (2 float4). In-place is
// safe: each thread writes only the elements it read.
__global__ __launch_bounds__(256)
void k_softmax(float* __restrict__ s) {
    const int tid  = threadIdx.x;
    const int wave = tid >> 6;
    const int lane = tid & 63;
    float4* row4 = (float4*)(s + (size_t)blockIdx.x * N_DIM);

    __shared__ float red[4];

    float4 a = row4[tid];
    float4 c = row4[tid + 256];

    float m0 = fmaxf(fmaxf(fmaxf(a.x, a.y), fmaxf(a.z, a.w)),
                     fmaxf(fmaxf(c.x, c.y), fmaxf(c.z, c.w)));
    #pragma unroll
    for (int m = 1; m < 64; m <<= 1) m0 = fmaxf(m0, __shfl_xor(m0, m, 64));
    if (lane == 0) red[wave] = m0;
    __syncthreads();
    const float gmax = fmaxf(fmaxf(red[0], red[1]), fmaxf(red[2], red[3]));
    __syncthreads();

    a.x = __expf(a.x - gmax); a.y = __expf(a.y - gmax);
    a.z = __expf(a.z - gmax); a.w = __expf(a.w - gmax);
    c.x = __expf(c.x - gmax); c.y = __expf(c.y - gmax);
    c.z = __expf(c.z - gmax); c.w = __expf(c.w - gmax);

    float sum = a.x + a.y + a.z + a.w + c.x + c.y + c.z + c.w;
    #pragma unroll
    for (int m = 1; m < 64; m <<= 1) sum += __shfl_xor(sum, m, 64);
    if (lane == 0) red[wave] = sum;
    __syncthreads();
    const float inv = 1.0f / (red[0] + red[1] + red[2] + red[3]);

    a.x *= inv; a.y *= inv; a.z *= inv; a.w *= inv;
    c.x *= inv; c.y *= inv; c.z *= inv; c.w *= inv;
    row4[tid]       = a;
    row4[tid + 256] = c;
}

// ---- K3: out[r,:] = p[r] * ctx[r,:] ----
// 64 consecutive rows per block (2048 float4); p staged in LDS (broadcast
// reads). Blocks walk the tensor BACKWARD (LIFO vs K1) and use nt
// loads/stores so output traffic doesn't evict cached ctx.
__global__ __launch_bounds__(256)
void k_scale(const float* __restrict__ ctx, const float* __restrict__ p,
             float* __restrict__ out) {
    const int tid = threadIdx.x;
    const int rb  = gridDim.x - 1 - blockIdx.x;         // reverse order
    const size_t base_row = (size_t)rb * 64;

    __shared__ float sp[64];
    if (tid < 64) sp[tid] = p[base_row + tid];
    __syncthreads();

    const f4v* c4 = (const f4v*)ctx + base_row * DVEC;
    f4v*       o4 = (f4v*)out       + base_row * DVEC;

    #pragma unroll
    for (int i = 0; i < 8; ++i) {
        const int f = i * 256 + tid;
        const float w = sp[f >> 5];
        f4v v = __builtin_nontemporal_load(&c4[f]);
        v *= w;
        __builtin_nontemporal_store(v, &o4[f]);
    }
}

extern "C" void kernel_launch(void* const* d_in, const int* in_sizes, int n_in,
                              void* d_out, int out_size, void* d_ws, size_t ws_size,
                              hipStream_t stream) {
    (void)in_sizes; (void)n_in; (void)out_size; (void)ws_size;
    // d_in[0] = targetsentence_emb (unused: cancels in softmax)
    // d_in[1] = context_emb, d_in[2] = W, d_in[3] = b (unused: cancels)
    const float* ctx = (const float*)d_in[1];
    const float* W   = (const float*)d_in[2];
    float* out       = (float*)d_out;
    float* scores    = (float*)d_ws;   // B*N floats = 2 MiB

    hipLaunchKernelGGL(k_scores,  dim3(B_DIM * N_DIM / 8), dim3(256), 0, stream,
                       ctx, W, scores);
    hipLaunchKernelGGL(k_softmax, dim3(B_DIM),             dim3(256), 0, stream,
                       scores);
    hipLaunchKernelGGL(k_scale,   dim3(B_DIM * N_DIM / 64), dim3(256), 0, stream,
                       ctx, scores, out);
}